// Round 1
// baseline (373.506 us; speedup 1.0000x reference)
//
#include <hip/hip_runtime.h>
#include <hip/hip_bf16.h>
#include <cstdint>

typedef unsigned short u16;
typedef __attribute__((ext_vector_type(8))) short short8;
typedef __attribute__((ext_vector_type(4))) float f32x4;

#define NB   32
#define CIN  256
#define HH   56
#define WWID 56
#define HP   58
#define WP   58
#define COUT 256
#define NSPAT (NB*HH*WWID)   // 100352 = 784*128

// round-to-nearest-even f32 -> bf16 bits
__device__ __forceinline__ u16 f2bf(float f) {
  uint32_t u = __float_as_uint(f);
  u += 0x7FFFu + ((u >> 16) & 1u);
  return (u16)(u >> 16);
}

// global -> LDS direct copy, 16B per lane. LDS dest must be wave-uniform.
__device__ __forceinline__ void gload16(const void* g, void* lds) {
  auto* gp = reinterpret_cast<const __attribute__((address_space(1))) uint32_t*>(
      reinterpret_cast<uintptr_t>(g));
  auto* lp = reinterpret_cast<__attribute__((address_space(3))) uint32_t*>(
      reinterpret_cast<uintptr_t>(lds));
  __builtin_amdgcn_global_load_lds(gp, lp, 16, 0, 0);
}

// ---------------------------------------------------------------------------
// prep_x: bin_active + bf16 cast + NCHW->padded-NHWC transpose.
// grid (32, 58), block 256. Border rows/cols written as zeros (d_ws is poisoned).
// xbp layout: [n][hp][wp][ci] bf16, hp/wp in [0,58), interior = x row (hp-1, wp-1).
// ---------------------------------------------------------------------------
__global__ __launch_bounds__(256) void prep_x_kernel(const float* __restrict__ x,
                                                     u16* __restrict__ xbp) {
  const int n = blockIdx.x, hp = blockIdx.y, t = threadIdx.x;
  u16* row = xbp + ((size_t)(n*HP + hp))*WP*CIN;
  if (hp == 0 || hp == HP-1) {           // top/bottom halo row: all zeros
    uint32_t* p = (uint32_t*)row;
    for (int i = t; i < WP*CIN/2; i += 256) p[i] = 0;
    return;
  }
  const int h = hp - 1;
  // LDS tile: [c][15 pads of 14 used][4 w] -> (c*15 + w4)*4 + (w&3), ushort
  __shared__ u16 lds[CIN*15*4];
  if (t < 224) {
    const int f4 = t % 14, c0 = t / 14;
    #pragma unroll
    for (int ci = 0; ci < 16; ci++) {
      const int c = c0*16 + ci;
      const float4 v = *(const float4*)(x + (((size_t)n*CIN + c)*HH + h)*WWID + f4*4);
      const float m01 = 0.5f*(fabsf(v.x)+fabsf(v.y));
      const float m23 = 0.5f*(fabsf(v.z)+fabsf(v.w));
      ushort4 o;
      o.x = f2bf(v.x == 0.f ? 0.f : copysignf(m01, v.x));
      o.y = f2bf(v.y == 0.f ? 0.f : copysignf(m01, v.y));
      o.z = f2bf(v.z == 0.f ? 0.f : copysignf(m23, v.z));
      o.w = f2bf(v.w == 0.f ? 0.f : copysignf(m23, v.w));
      *(ushort4*)&lds[(c*15 + f4)*4] = o;
    }
  }
  __syncthreads();
  if (t < 128) {
    // left/right halo columns
    ((uint32_t*)row)[t] = 0;                       // wp = 0
    ((uint32_t*)(row + (WP-1)*CIN))[t] = 0;        // wp = 57
    const int c0 = 2*t;
    #pragma unroll
    for (int w = 0; w < WWID; w++) {
      const uint32_t u0 = lds[(c0*15 + (w>>2))*4 + (w&3)];
      const uint32_t u1 = lds[((c0+1)*15 + (w>>2))*4 + (w&3)];
      ((uint32_t*)(row + (w+1)*CIN))[t] = u0 | (u1 << 16);
    }
  }
}

// ---------------------------------------------------------------------------
// prep_w: weight [co][ci][kh][kw] fp32 -> wr [kh*3+kw][co][ci] bf16
// ---------------------------------------------------------------------------
__global__ __launch_bounds__(256) void prep_w_kernel(const float* __restrict__ wsrc,
                                                     u16* __restrict__ wr) {
  const int idx = blockIdx.x*256 + threadIdx.x;   // co*256 + ci
  const int co = idx >> 8, ci = idx & 255;
  const float* s = wsrc + (size_t)idx*9;
  #pragma unroll
  for (int p = 0; p < 9; p++)
    wr[((size_t)p*COUT + co)*CIN + ci] = f2bf(s[p]);
}

// ---------------------------------------------------------------------------
// conv: implicit GEMM. M = co (A = weights), N = flattened spatial (B = xbp).
// 128x128 tile, 4 waves (2 co x 2 spatial), 16x16x32 bf16 MFMA, BK = 64,
// K loop = 9 kernel positions x 4 ci-chunks. XOR-swizzled LDS (chunk ^= row&7)
// applied on the global SOURCE side (linear global_load_lds dest) and on
// ds_read fragment addresses.
// grid (784, 2), block 256.
// ---------------------------------------------------------------------------
__global__ __launch_bounds__(256) void conv_kernel(const u16* __restrict__ xbp,
                                                   const u16* __restrict__ wr,
                                                   const float* __restrict__ bias,
                                                   float* __restrict__ out) {
  __shared__ u16 ldsA[128*64];   // weights tile: [co_row][ci]  (swizzled)
  __shared__ u16 ldsB[128*64];   // xb tile:      [m_row][ci]   (swizzled)
  const int t = threadIdx.x;
  const int wv = t >> 6, l = t & 63;
  const int mtile = blockIdx.x, ntile = blockIdx.y;

  // staging constants: thread stages chunk c=l&7 of row r=(i*4+wv)*8+(l>>3);
  // source chunk is (l&7)^(l>>3) (r&7 == l>>3 since row base is 8-aligned)
  const int cs8 = (((l & 7) ^ (l >> 3)) << 3);     // element offset in row
  const int rb  = wv*8 + (l >> 3);

  int base0[4];
  #pragma unroll
  for (int i = 0; i < 4; i++) {
    const int m  = mtile*128 + i*32 + rb;
    const int n  = m / 3136, hw = m % 3136;
    base0[i] = ((n*HP + hw/WWID)*WP + (hw%WWID))*CIN;  // padded-NHWC elem index
  }

  f32x4 acc[4][4];
  #pragma unroll
  for (int a = 0; a < 4; a++)
    #pragma unroll
    for (int b = 0; b < 4; b++) {
      acc[a][b][0] = 0.f; acc[a][b][1] = 0.f; acc[a][b][2] = 0.f; acc[a][b][3] = 0.f;
    }

  for (int ks = 0; ks < 36; ks++) {
    const int pos = ks >> 2, cb = ks & 3;
    const int posoff = ((pos/3)*WP + (pos%3))*CIN;   // halo window offset
    const int koff = cb*64 + cs8;
    #pragma unroll
    for (int i = 0; i < 4; i++) {
      const u16* gA = wr + (((pos*COUT + ntile*128 + i*32 + rb) << 8) + koff);
      gload16(gA, &ldsA[(i*4 + wv)*512]);
      const u16* gB = xbp + base0[i] + posoff + koff;
      gload16(gB, &ldsB[(i*4 + wv)*512]);
    }
    __syncthreads();
    #pragma unroll
    for (int kk = 0; kk < 2; kk++) {
      const int ch = (l >> 4) + 4*kk;     // logical 16B chunk (k index / 8)
      short8 af[4], bfr[4];
      #pragma unroll
      for (int mi = 0; mi < 4; mi++) {
        const int r = (wv & 1)*64 + mi*16 + (l & 15);
        af[mi] = *(const short8*)&ldsA[r*64 + ((ch ^ (r & 7)) << 3)];
      }
      #pragma unroll
      for (int ni = 0; ni < 4; ni++) {
        const int r = (wv >> 1)*64 + ni*16 + (l & 15);
        bfr[ni] = *(const short8*)&ldsB[r*64 + ((ch ^ (r & 7)) << 3)];
      }
      #pragma unroll
      for (int mi = 0; mi < 4; mi++)
        #pragma unroll
        for (int ni = 0; ni < 4; ni++)
          acc[mi][ni] = __builtin_amdgcn_mfma_f32_16x16x32_bf16(af[mi], bfr[ni], acc[mi][ni], 0, 0, 0);
    }
    __syncthreads();
  }

  // epilogue: D col (lane&15) = spatial (contiguous w), D row = co
  const int co0 = ntile*128 + (wv & 1)*64 + ((l >> 4) << 2);
  float bi[4][4];
  #pragma unroll
  for (int mi = 0; mi < 4; mi++)
    #pragma unroll
    for (int j = 0; j < 4; j++)
      bi[mi][j] = bias[co0 + mi*16 + j];
  const int mb = mtile*128 + (wv >> 1)*64 + (l & 15);
  #pragma unroll
  for (int ni = 0; ni < 4; ni++) {
    const int m = mb + ni*16;
    const int n = m / 3136, hw = m % 3136;
    float* orow = out + (size_t)n*COUT*3136 + hw;
    #pragma unroll
    for (int mi = 0; mi < 4; mi++) {
      #pragma unroll
      for (int j = 0; j < 4; j++)
        orow[(size_t)(co0 + mi*16 + j)*3136] = acc[mi][ni][j] + bi[mi][j];
    }
  }
}

extern "C" void kernel_launch(void* const* d_in, const int* in_sizes, int n_in,
                              void* d_out, int out_size, void* d_ws, size_t ws_size,
                              hipStream_t stream) {
  const float* x      = (const float*)d_in[0];
  const float* weight = (const float*)d_in[1];
  const float* bias   = (const float*)d_in[2];
  float* out = (float*)d_out;

  u16* xbp = (u16*)d_ws;                                  // 32*58*58*256 bf16 = 55.1 MB
  u16* wrr = xbp + (size_t)NB*HP*WP*CIN;                  // 9*256*256 bf16 = 1.18 MB

  prep_x_kernel<<<dim3(NB, HP), 256, 0, stream>>>(x, xbp);
  prep_w_kernel<<<dim3(256), 256, 0, stream>>>(weight, wrr);
  conv_kernel<<<dim3(NSPAT/128, 2), 256, 0, stream>>>(xbp, wrr, bias, out);
}

// Round 3
// 334.113 us; speedup vs baseline: 1.1179x; 1.1179x over previous
//
#include <hip/hip_runtime.h>
#include <hip/hip_bf16.h>
#include <cstdint>

typedef unsigned short u16;
typedef __attribute__((ext_vector_type(8))) short short8;
typedef __attribute__((ext_vector_type(4))) float f32x4;

#define NB   32
#define CIN  256
#define HH   56
#define WWID 56
#define HP   58
#define WP   58
#define COUT 256
#define NSPAT (NB*HH*WWID)   // 100352 = 784*128

// round-to-nearest-even f32 -> bf16 bits
__device__ __forceinline__ u16 f2bf(float f) {
  uint32_t u = __float_as_uint(f);
  u += 0x7FFFu + ((u >> 16) & 1u);
  return (u16)(u >> 16);
}

// global -> LDS direct copy, 16B per lane. LDS dest must be wave-uniform.
__device__ __forceinline__ void gload16(const void* g, void* lds) {
  auto* gp = reinterpret_cast<const __attribute__((address_space(1))) uint32_t*>(
      reinterpret_cast<uintptr_t>(g));
  auto* lp = reinterpret_cast<__attribute__((address_space(3))) uint32_t*>(
      reinterpret_cast<uintptr_t>(lds));
  __builtin_amdgcn_global_load_lds(gp, lp, 16, 0, 0);
}

// ---------------------------------------------------------------------------
// prep_x: bin_active + bf16 cast + NCHW->padded-NHWC transpose.
// grid (32, 58), block 256. Halo rows/cols zeroed.
// xbp layout: [n][hp][wp][ci] bf16, interior = x row (hp-1, wp-1).
// LDS tile [w][c] bf16, 16B-chunk XOR swizzle chunk' = chunk ^ ((w>>2)&7).
// BOTH sides use the 3-bit mask (round-2 bug: write used 4+ bits, read 3).
//  - phase-2 b128 reads: 32 lanes span one w row; XOR is a permutation of the
//    32 chunks -> 512B sequential -> conflict-free.
// ---------------------------------------------------------------------------
__global__ __launch_bounds__(256) void prep_x_kernel(const float* __restrict__ x,
                                                     u16* __restrict__ xbp) {
  const int n = blockIdx.x, hp = blockIdx.y, t = threadIdx.x;
  u16* row = xbp + ((size_t)(n*HP + hp))*WP*CIN;
  if (hp == 0 || hp == HP-1) {           // top/bottom halo row: all zeros
    uint32_t* p = (uint32_t*)row;
    for (int i = t; i < WP*CIN/2; i += 256) p[i] = 0;
    return;
  }
  const int h = hp - 1;
  __shared__ u16 lds[HH*CIN];            // 28 KB
  if (t < 224) {
    const int f4 = t % 14, c0 = (t / 14) * 16;
    const int sw = f4 & 7;               // w>>2 == f4 for all 4 j below
    #pragma unroll
    for (int ci = 0; ci < 16; ci++) {
      const int c = c0 + ci;
      const float4 v = *(const float4*)(x + (((size_t)n*CIN + c)*HH + h)*WWID + f4*4);
      const float m01 = 0.5f*(fabsf(v.x)+fabsf(v.y));
      const float m23 = 0.5f*(fabsf(v.z)+fabsf(v.w));
      u16 o[4];
      o[0] = f2bf(v.x == 0.f ? 0.f : copysignf(m01, v.x));
      o[1] = f2bf(v.y == 0.f ? 0.f : copysignf(m01, v.y));
      o[2] = f2bf(v.z == 0.f ? 0.f : copysignf(m23, v.z));
      o[3] = f2bf(v.w == 0.f ? 0.f : copysignf(m23, v.w));
      const int cs = ((((c >> 3) ^ sw) & 31) << 3) | (c & 7);
      #pragma unroll
      for (int j = 0; j < 4; j++)
        lds[(f4*4 + j)*CIN + cs] = o[j];
    }
  }
  __syncthreads();
  // side halo columns
  if (t < 128) ((uint32_t*)row)[t] = 0;                            // wp = 0
  else ((uint32_t*)(row + (WP-1)*CIN))[t-128] = 0;                 // wp = 57
  // interior: 56 w * 32 chunks of 16B = 1792 chunks, 7 per thread
  #pragma unroll
  for (int it = 0; it < 7; it++) {
    const int q = it*256 + t;
    const int w = q >> 5, ck = q & 31;
    const short8 v = *(const short8*)&lds[w*CIN + ((ck ^ ((w >> 2) & 7)) << 3)];
    *(short8*)(row + (size_t)(w+1)*CIN + (ck << 3)) = v;
  }
}

// ---------------------------------------------------------------------------
// prep_w: weight [co][ci][kh][kw] fp32 -> wr [kh*3+kw][co][ci] bf16
// ---------------------------------------------------------------------------
__global__ __launch_bounds__(256) void prep_w_kernel(const float* __restrict__ wsrc,
                                                     u16* __restrict__ wr) {
  const int idx = blockIdx.x*256 + threadIdx.x;   // co*256 + ci
  const int co = idx >> 8, ci = idx & 255;
  const float* s = wsrc + (size_t)idx*9;
  #pragma unroll
  for (int p = 0; p < 9; p++)
    wr[((size_t)p*COUT + co)*CIN + ci] = f2bf(s[p]);
}

// ---------------------------------------------------------------------------
// conv: implicit GEMM. M = co (A = weights), N = flattened spatial (B = xbp).
// 128x128 tile, 4 waves (2 co x 2 spatial), 16x16x32 bf16 MFMA, BK = 64,
// K loop = 9 kernel positions x 4 ci-chunks = 36 steps.
// Double-buffered LDS (T3-minimum): stage step t+1 before computing step t,
// ONE __syncthreads per step -> gload latency hides under MFMA.
// XCD swizzle (T1): 1568 blocks, each XCD gets 98 contiguous spatial mtiles.
// XOR LDS swizzle (chunk ^= row&7) on source side + ds_read addrs.
// ---------------------------------------------------------------------------
__global__ __launch_bounds__(256) void conv_kernel(const u16* __restrict__ xbp,
                                                   const u16* __restrict__ wr,
                                                   const float* __restrict__ bias,
                                                   float* __restrict__ out) {
  __shared__ u16 ldsA[2][128*64];   // weights tiles (swizzled)
  __shared__ u16 ldsB[2][128*64];   // xb tiles (swizzled)
  const int t = threadIdx.x;
  const int wv = t >> 6, l = t & 63;
  const int bid = blockIdx.x;
  const int b9 = (bid & 7)*196 + (bid >> 3);     // XCD-contiguous remap (1568%8==0)
  const int ntile = b9 & 1, mtile = b9 >> 1;

  // staging: thread stages chunk c=l&7 of row r=(i*4+wv)*8+(l>>3);
  // source chunk is (l&7)^(l>>3) (row&7 == l>>3 since row base is 8-aligned)
  const int cs8 = (((l & 7) ^ (l >> 3)) << 3);
  const int rb  = wv*8 + (l >> 3);

  int base0[4];
  #pragma unroll
  for (int i = 0; i < 4; i++) {
    const int m  = mtile*128 + i*32 + rb;
    const int n  = m / 3136, hw = m % 3136;
    base0[i] = ((n*HP + hw/WWID)*WP + (hw%WWID))*CIN;  // padded-NHWC elem index
  }

  auto STAGE = [&](int buf, int ks) {
    const int pos = ks >> 2, cb = ks & 3;
    const int posoff = ((pos/3)*WP + (pos%3))*CIN;
    const int koff = cb*64 + cs8;
    #pragma unroll
    for (int i = 0; i < 4; i++) {
      const u16* gA = wr + (((pos*COUT + ntile*128 + i*32 + rb) << 8) + koff);
      gload16(gA, &ldsA[buf][(i*4 + wv)*512]);
      const u16* gB = xbp + base0[i] + posoff + koff;
      gload16(gB, &ldsB[buf][(i*4 + wv)*512]);
    }
  };

  f32x4 acc[4][4];
  #pragma unroll
  for (int a = 0; a < 4; a++)
    #pragma unroll
    for (int b = 0; b < 4; b++) {
      acc[a][b][0] = 0.f; acc[a][b][1] = 0.f; acc[a][b][2] = 0.f; acc[a][b][3] = 0.f;
    }

  STAGE(0, 0);
  __syncthreads();
  int cur = 0;
  for (int ks = 0; ks < 36; ks++) {
    if (ks < 35) STAGE(cur ^ 1, ks + 1);
    #pragma unroll
    for (int kk = 0; kk < 2; kk++) {
      const int ch = (l >> 4) + 4*kk;     // logical 16B chunk (k index / 8)
      short8 af[4], bfr[4];
      #pragma unroll
      for (int mi = 0; mi < 4; mi++) {
        const int r = (wv & 1)*64 + mi*16 + (l & 15);
        af[mi] = *(const short8*)&ldsA[cur][r*64 + ((ch ^ (r & 7)) << 3)];
      }
      #pragma unroll
      for (int ni = 0; ni < 4; ni++) {
        const int r = (wv >> 1)*64 + ni*16 + (l & 15);
        bfr[ni] = *(const short8*)&ldsB[cur][r*64 + ((ch ^ (r & 7)) << 3)];
      }
      #pragma unroll
      for (int mi = 0; mi < 4; mi++)
        #pragma unroll
        for (int ni = 0; ni < 4; ni++)
          acc[mi][ni] = __builtin_amdgcn_mfma_f32_16x16x32_bf16(af[mi], bfr[ni], acc[mi][ni], 0, 0, 0);
    }
    __syncthreads();   // drains stage(t+1) (overlapped with the MFMAs above)
    cur ^= 1;
  }

  // epilogue: D col (lane&15) = spatial (contiguous w), D row = co
  const int co0 = ntile*128 + (wv & 1)*64 + ((l >> 4) << 2);
  float bi[4][4];
  #pragma unroll
  for (int mi = 0; mi < 4; mi++)
    #pragma unroll
    for (int j = 0; j < 4; j++)
      bi[mi][j] = bias[co0 + mi*16 + j];
  const int mb = mtile*128 + (wv >> 1)*64 + (l & 15);
  #pragma unroll
  for (int ni = 0; ni < 4; ni++) {
    const int m = mb + ni*16;
    const int n = m / 3136, hw = m % 3136;
    float* orow = out + (size_t)n*COUT*3136 + hw;
    #pragma unroll
    for (int mi = 0; mi < 4; mi++) {
      #pragma unroll
      for (int j = 0; j < 4; j++)
        orow[(size_t)(co0 + mi*16 + j)*3136] = acc[mi][ni][j] + bi[mi][j];
    }
  }
}

extern "C" void kernel_launch(void* const* d_in, const int* in_sizes, int n_in,
                              void* d_out, int out_size, void* d_ws, size_t ws_size,
                              hipStream_t stream) {
  const float* x      = (const float*)d_in[0];
  const float* weight = (const float*)d_in[1];
  const float* bias   = (const float*)d_in[2];
  float* out = (float*)d_out;

  u16* xbp = (u16*)d_ws;                                  // 32*58*58*256 bf16 = 55.1 MB
  u16* wrr = xbp + (size_t)NB*HP*WP*CIN;                  // 9*256*256 bf16 = 1.18 MB

  prep_x_kernel<<<dim3(NB, HP), 256, 0, stream>>>(x, xbp);
  prep_w_kernel<<<dim3(256), 256, 0, stream>>>(weight, wrr);
  conv_kernel<<<dim3(NSPAT/128 * 2), 256, 0, stream>>>(xbp, wrr, bias, out);
}